// Round 13
// baseline (417.261 us; speedup 1.0000x reference)
//
#include <hip/hip_runtime.h>
#include <cstdint>

// RingAttractorNetwork: B=2048, N_EXC=1024, N_INH=256, 10 steps.
// Round 13: r5 baseline (best measured, 394us: 64x64 tiles, BK=64, 0-conflict
// XOR swizzle, 2-buf barrier-first gload_lds pipeline, inline Poisson) + ONE
// change: XCD-aware block mapping (T1). Grid flattened to 1D 640; physical
// block p -> XCD p&7 (round-robin assumption); each XCD owns an 8x10
// (batch-x x role-y) rectangle so its ~2.5MB working set (weights+slices)
// fits its 4MB L2 and the read-only weights stay L2-resident across all 10
// dispatches. Pure index permutation - numerics identical (absmax 0.0078).

#define N_EXC 1024
#define N_INH 256
#define BATCH 2048
#define STEPS 10
#define MAX_POIS 32

typedef short s16x8 __attribute__((ext_vector_type(8)));
typedef float f32x4 __attribute__((ext_vector_type(4)));

typedef __attribute__((address_space(1))) const void GV;
typedef __attribute__((address_space(3))) void LV;

struct U2 { uint32_t x, y; };

__device__ __forceinline__ uint32_t rotl32(uint32_t v, int r) {
  return (v << r) | (v >> (32 - r));
}

// JAX threefry2x32 (20 rounds).
__device__ __forceinline__ U2 threefry(U2 k, uint32_t x0, uint32_t x1) {
  uint32_t ks0 = k.x, ks1 = k.y, ks2 = k.x ^ k.y ^ 0x1BD11BDAu;
  x0 += ks0; x1 += ks1;
#define TF_R4(a,b,c,d) \
  x0 += x1; x1 = rotl32(x1,a); x1 ^= x0; \
  x0 += x1; x1 = rotl32(x1,b); x1 ^= x0; \
  x0 += x1; x1 = rotl32(x1,c); x1 ^= x0; \
  x0 += x1; x1 = rotl32(x1,d); x1 ^= x0;
  TF_R4(13,15,26,6)  x0 += ks1; x1 += ks2 + 1u;
  TF_R4(17,29,16,24) x0 += ks2; x1 += ks0 + 2u;
  TF_R4(13,15,26,6)  x0 += ks0; x1 += ks1 + 3u;
  TF_R4(17,29,16,24) x0 += ks1; x1 += ks2 + 4u;
  TF_R4(13,15,26,6)  x0 += ks2; x1 += ks0 + 5u;
#undef TF_R4
  U2 r; r.x = x0; r.y = x1; return r;
}

// Knuth Poisson with partitionable random_bits: bits = h.x ^ h.y,
// h = threefry(subkey_n, 0, e). Returns (poisson - lam).
__device__ __forceinline__ float poisson_mean_sub(uint32_t e,
                                                  const U2* __restrict__ sk,
                                                  float lam) {
  float neg_lam = -lam;
  float lp = 0.0f;
  int k = 0;
#pragma unroll 1
  for (int n = 0; n < MAX_POIS; ++n) {
    if (!(lp > neg_lam)) break;
    k++;
    U2 h = threefry(sk[n], 0u, e);
    uint32_t bits = h.x ^ h.y;
    float u = __uint_as_float((bits >> 9) | 0x3f800000u) - 1.0f;
    lp += logf(u);
  }
  return (float)(k - 1) - lam;
}

__device__ __forceinline__ unsigned short f2b(float f) {
  uint32_t u = __float_as_uint(f);
  return (unsigned short)((u + 0x7FFFu + ((u >> 16) & 1u)) >> 16);  // RNE
}

__device__ __forceinline__ void gload16(const void* g, void* l) {
  __builtin_amdgcn_global_load_lds((GV*)g, (LV*)l, 16, 0, 0);
}

// Subkey chains: key = fold_in(key(42), t), split -> (ke, ki); iterated
// fold-like splits give the per-while-iteration uniform subkeys.
__global__ void keys_kernel(U2* subk_e, U2* subk_i) {
  int tid = threadIdx.x;
  if (tid >= 2 * STEPS) return;
  int t = tid >> 1;
  bool is_i = tid & 1;
  U2 base; base.x = 0u; base.y = 42u;
  U2 folded = threefry(base, 0u, (uint32_t)t);        // fold_in
  U2 ke = threefry(folded, 0u, 0u);                   // partitionable split
  U2 ki = threefry(folded, 0u, 1u);
  U2 rng = is_i ? ki : ke;
  U2* dst = (is_i ? subk_i : subk_e) + t * MAX_POIS;
  for (int n = 0; n < MAX_POIS; ++n) {
    dst[n] = threefry(rng, 0u, 1u);                   // subkey
    rng = threefry(rng, 0u, 0u);                      // carried rng
  }
}

// W_EE ring weights -> bf16. Row-normalize (incl. diagonal) in f32, then zero diag.
__global__ __launch_bounds__(256) void wee_kernel(const float* __restrict__ sigma_p,
                                                  unsigned short* __restrict__ W) {
  int i = blockIdx.x;
  int tid = threadIdx.x;
  float sigma = *sigma_p;
  const float twopi = 6.28318530717958647692f;
  const float delta = twopi / 1023.0f;
  float ai = (float)i * delta;
  float w[4];
  float s = 0.0f;
#pragma unroll
  for (int q = 0; q < 4; ++q) {
    int j = tid + q * 256;
    float aj = (float)j * delta;
    float d = aj - ai;
    float wd = atan2f(sinf(d), cosf(d));
    float x = wd / sigma;
    float v = expf(-0.5f * x * x);
    w[q] = v;
    s += v;
  }
  __shared__ float red[256];
  red[tid] = s;
  __syncthreads();
  for (int off = 128; off > 0; off >>= 1) {
    if (tid < off) red[tid] += red[tid + off];
    __syncthreads();
  }
  float sum = red[0];
#pragma unroll
  for (int q = 0; q < 4; ++q) {
    int j = tid + q * 256;
    W[i * N_EXC + j] = (j == i) ? (unsigned short)0 : f2b(w[q] / sum);
  }
}

// Transposed/converted weights + h->bf16.
__global__ void setup_kernel(const float* __restrict__ W_EI, const float* __restrict__ W_IE,
                             const float* __restrict__ h,
                             unsigned short* __restrict__ W_EIT,   // [256][1024]
                             unsigned short* __restrict__ W_IET,   // [1024][256]
                             unsigned short* __restrict__ hb) {
  int tid = blockIdx.x * blockDim.x + threadIdx.x;
  int nt = gridDim.x * blockDim.x;
  for (int i = tid; i < BATCH * N_EXC; i += nt) hb[i] = f2b(h[i]);
  for (int i = tid; i < N_INH * N_EXC; i += nt) {
    int r = i >> 10, c = i & 1023;
    W_EIT[i] = f2b(W_EI[c * N_INH + r]);
  }
  for (int i = tid; i < N_EXC * N_INH; i += nt) {
    int r = i >> 8, c = i & 255;
    W_IET[i] = f2b(W_IE[c * N_EXC + r]);
  }
}

// Pipelined 64x64-tile GEMM phase, double-buffered, gload_lds-staged, XOR-swizzled.
// LDS chunk j (16B) of a [64][64]-bf16 tile holds global (row=j>>3, col16=(j&7)^(row&7)).
// Read of logical (r,c16) -> byte (r<<7) | ((c16^(r&7))<<4). Swizzle on BOTH the
// global source and the ds_read (rule 21); 0 measured conflicts (r8). Loop:
// [__syncthreads; prefetch T(kt+1)->buf^1; compute T(kt)]. NT even.
#define PIPE_GEMM(APTR, LDA, AROW0, BPTR, LDB, BROW0, KLEN, ACC)                \
  {                                                                             \
    const int NT = (KLEN) / 64;                                                 \
    int c0 = wave * 128 + lane;                                                 \
    int c1 = c0 + 64;                                                           \
    int r0 = c0 >> 3, q0 = ((c0 & 7) ^ (r0 & 7)) << 3;                          \
    int r1 = c1 >> 3, q1 = ((c1 & 7) ^ (r1 & 7)) << 3;                          \
    const unsigned short* ap0 = (APTR) + (size_t)((AROW0) + r0) * (LDA) + q0;   \
    const unsigned short* ap1 = (APTR) + (size_t)((AROW0) + r1) * (LDA) + q1;   \
    const unsigned short* bp0 = (BPTR) + (size_t)((BROW0) + r0) * (LDB) + q0;   \
    const unsigned short* bp1 = (BPTR) + (size_t)((BROW0) + r1) * (LDB) + q1;   \
    char* la0 = (char*)As + wave * 2048;                                        \
    char* la1 = la0 + 1024;                                                     \
    char* lb0 = (char*)Bs + wave * 2048;                                        \
    char* lb1 = lb0 + 1024;                                                     \
    gload16(ap0, la0); gload16(ap1, la1);                                       \
    gload16(bp0, lb0); gload16(bp1, lb1);                                       \
    int cur = 0;                                                                \
    int raf0 = wr * 32 + l16, raf1 = raf0 + 16;                                 \
    int rbf0 = wc * 32 + l16, rbf1 = rbf0 + 16;                                 \
    int aA0 = (raf0 << 7) | ((lhi ^ (raf0 & 7)) << 4);                          \
    int aA1 = (raf1 << 7) | ((lhi ^ (raf1 & 7)) << 4);                          \
    int aB0 = (rbf0 << 7) | ((lhi ^ (rbf0 & 7)) << 4);                          \
    int aB1 = (rbf1 << 7) | ((lhi ^ (rbf1 & 7)) << 4);                          \
    for (int kt = 0; kt < NT; ++kt) {                                           \
      __syncthreads();                                                          \
      if (kt + 1 < NT) {                                                        \
        int k0 = (kt + 1) * 64;                                                 \
        int nb = (cur ^ 1) * 8192;                                              \
        gload16(ap0 + k0, la0 + nb); gload16(ap1 + k0, la1 + nb);               \
        gload16(bp0 + k0, lb0 + nb); gload16(bp1 + k0, lb1 + nb);               \
      }                                                                         \
      const char* ab = (const char*)As + cur * 8192;                            \
      const char* bb = (const char*)Bs + cur * 8192;                            \
      _Pragma("unroll")                                                         \
      for (int ks = 0; ks < 2; ++ks) {                                          \
        int kx = ks << 6;                                                       \
        s16x8 af0 = *(const s16x8*)(ab + (aA0 ^ kx));                           \
        s16x8 af1 = *(const s16x8*)(ab + (aA1 ^ kx));                           \
        s16x8 bf0 = *(const s16x8*)(bb + (aB0 ^ kx));                           \
        s16x8 bf1 = *(const s16x8*)(bb + (aB1 ^ kx));                           \
        ACC[0][0] = __builtin_amdgcn_mfma_f32_16x16x32_bf16(af0, bf0, ACC[0][0], 0, 0, 0); \
        ACC[0][1] = __builtin_amdgcn_mfma_f32_16x16x32_bf16(af0, bf1, ACC[0][1], 0, 0, 0); \
        ACC[1][0] = __builtin_amdgcn_mfma_f32_16x16x32_bf16(af1, bf0, ACC[1][0], 0, 0, 0); \
        ACC[1][1] = __builtin_amdgcn_mfma_f32_16x16x32_bf16(af1, bf1, ACC[1][1], 0, 0, 0); \
      }                                                                         \
      cur ^= 1;                                                                 \
    }                                                                           \
  }

// Fused step, 1D grid of 640 blocks with XCD-aware decode:
//   p & 7       -> XCD (observed round-robin assignment)
//   XCD k owns  x in [8*(k&3), +8), y-role in [10*(k>>2), +10)
// so each XCD's weight slice + A slices (~2.5MB) fit its 4MB L2, and weights
// stay L2-resident across the 10 step dispatches (L2 persists across launches).
__global__ __launch_bounds__(256) void step_kernel(
    const float* __restrict__ re_in, const unsigned short* __restrict__ reb_in,
    const float* __restrict__ ri_in, const unsigned short* __restrict__ rib_in,
    const unsigned short* __restrict__ W_EEb, const unsigned short* __restrict__ W_IET,
    const unsigned short* __restrict__ W_EIT,
    const float* __restrict__ ext,
    const float* __restrict__ sc_gee, const float* __restrict__ sc_gei,
    const float* __restrict__ sc_gie, const float* __restrict__ sc_gin,
    const float* __restrict__ sc_rate_e, const float* __restrict__ sc_rate_i,
    const U2* __restrict__ subk_e, const U2* __restrict__ subk_i,
    float* __restrict__ re_out, unsigned short* __restrict__ reb_out,
    float* __restrict__ ri_out, unsigned short* __restrict__ rib_out) {
  __shared__ __align__(16) short As[2 * 4096];   // 2 bufs x 64x64 bf16, swizzled
  __shared__ __align__(16) short Bs[2 * 4096];
  int tid = threadIdx.x;
  int lane = tid & 63;
  int wave = tid >> 6;
  int wr = wave >> 1, wc = wave & 1;
  int l16 = lane & 15, lhi = lane >> 4;

  int p = blockIdx.x;                   // 0..639
  int xcd = p & 7;
  int idx = p >> 3;                     // 0..79
  int bx = ((xcd & 3) << 3) + (idx & 7);        // batch block 0..31
  int by = (xcd >> 2) * 10 + (idx >> 3);        // role 0..19

  int b0 = bx * 64;
  bool is_e = by < 16;
  int i0 = (is_e ? by : (by - 16)) * 64;

  f32x4 acc[2][2] = {};
  f32x4 acc2[2][2] = {};

  if (is_e) {
    PIPE_GEMM(reb_in, N_EXC, b0, W_EEb, N_EXC, i0, N_EXC, acc);       // NT=16
    if (rib_in != nullptr) {
      PIPE_GEMM(rib_in, N_INH, b0, W_IET, N_INH, i0, N_INH, acc2);    // NT=4
    }
    float gee = *sc_gee, gie = *sc_gie, gin = *sc_gin, rate = *sc_rate_e;
#pragma unroll
    for (int mm = 0; mm < 2; ++mm)
#pragma unroll
      for (int nn = 0; nn < 2; ++nn)
#pragma unroll
        for (int q = 0; q < 4; ++q) {
          int row = b0 + wr * 32 + mm * 16 + lhi * 4 + q;   // C/D: row=(lane>>4)*4+reg
          int col = i0 + wc * 32 + nn * 16 + l16;           //      col=lane&15
          int idx2 = row * N_EXC + col;
          float val = gee * acc[mm][nn][q] - gie * acc2[mm][nn][q] + gin * ext[idx2];
          val += poisson_mean_sub((uint32_t)idx2, subk_e, rate);
          float ro = re_in[idx2];
          float rn = ro + (0.1f * (fmaxf(val, 0.0f) - ro)) / 10.0f;
          rn = fmaxf(rn, 0.0f);
          re_out[idx2] = rn;
          reb_out[idx2] = f2b(rn);
        }
  } else {
    PIPE_GEMM(reb_in, N_EXC, b0, W_EIT, N_EXC, i0, N_EXC, acc);       // NT=16
    float gei = *sc_gei, rate = *sc_rate_i;
#pragma unroll
    for (int mm = 0; mm < 2; ++mm)
#pragma unroll
      for (int nn = 0; nn < 2; ++nn)
#pragma unroll
        for (int q = 0; q < 4; ++q) {
          int row = b0 + wr * 32 + mm * 16 + lhi * 4 + q;
          int col = i0 + wc * 32 + nn * 16 + l16;
          int idx2 = row * N_INH + col;
          float val = gei * acc[mm][nn][q];
          val += poisson_mean_sub((uint32_t)idx2, subk_i, rate);
          float rio = (ri_in != nullptr) ? ri_in[idx2] : 0.0f;
          float rn = rio + (0.1f * (fmaxf(val, 0.0f) - rio)) / 5.0f;
          rn = fmaxf(rn, 0.0f);
          ri_out[idx2] = rn;
          rib_out[idx2] = f2b(rn);
        }
  }
}

extern "C" void kernel_launch(void* const* d_in, const int* in_sizes, int n_in,
                              void* d_out, int out_size, void* d_ws, size_t ws_size,
                              hipStream_t stream) {
  const float* ext    = (const float*)d_in[0];
  const float* h      = (const float*)d_in[1];
  const float* sigma  = (const float*)d_in[2];
  const float* W_EI   = (const float*)d_in[3];
  const float* W_IE   = (const float*)d_in[4];
  const float* g_ee   = (const float*)d_in[5];
  const float* g_ei   = (const float*)d_in[6];
  const float* g_ie   = (const float*)d_in[7];
  const float* g_in   = (const float*)d_in[8];
  const float* rate_e = (const float*)d_in[9];
  const float* rate_i = (const float*)d_in[10];

  char* ws = (char*)d_ws;
  unsigned short* W_EEb = (unsigned short*)ws; ws += (size_t)N_EXC * N_EXC * 2;
  unsigned short* W_EIT = (unsigned short*)ws; ws += (size_t)N_INH * N_EXC * 2;
  unsigned short* W_IET = (unsigned short*)ws; ws += (size_t)N_EXC * N_INH * 2;
  float* reA            = (float*)ws;          ws += (size_t)BATCH * N_EXC * 4;
  unsigned short* rebA  = (unsigned short*)ws; ws += (size_t)BATCH * N_EXC * 2;
  unsigned short* rebB  = (unsigned short*)ws; ws += (size_t)BATCH * N_EXC * 2;
  float* riA            = (float*)ws;          ws += (size_t)BATCH * N_INH * 4;
  float* riB            = (float*)ws;          ws += (size_t)BATCH * N_INH * 4;
  unsigned short* ribA  = (unsigned short*)ws; ws += (size_t)BATCH * N_INH * 2;
  unsigned short* ribB  = (unsigned short*)ws; ws += (size_t)BATCH * N_INH * 2;
  U2* subk_e            = (U2*)ws;             ws += (size_t)STEPS * MAX_POIS * sizeof(U2);
  U2* subk_i            = (U2*)ws;             ws += (size_t)STEPS * MAX_POIS * sizeof(U2);
  float* re_dout = (float*)d_out;

  wee_kernel<<<dim3(N_EXC), dim3(256), 0, stream>>>(sigma, W_EEb);
  setup_kernel<<<dim3(512), dim3(256), 0, stream>>>(W_EI, W_IE, h, W_EIT, W_IET, rebB);
  keys_kernel<<<dim3(1), dim3(64), 0, stream>>>(subk_e, subk_i);

  for (int t = 0; t < STEPS; ++t) {
    const float* re_in          = (t == 0) ? h : ((t & 1) ? reA : re_dout);
    float* re_out               = (t & 1) ? re_dout : reA;
    const unsigned short* rb_in = (t & 1) ? rebA : rebB;   // t=0: rebB holds bf16(h)
    unsigned short* rb_out      = (t & 1) ? rebB : rebA;
    const float* ri_in          = (t == 0) ? nullptr : ((t & 1) ? riA : riB);
    float* ri_out               = (t & 1) ? riB : riA;
    const unsigned short* ib_in = (t == 0) ? nullptr : ((t & 1) ? ribA : ribB);
    unsigned short* ib_out      = (t & 1) ? ribB : ribA;

    step_kernel<<<dim3(640), dim3(256), 0, stream>>>(
        re_in, rb_in, ri_in, ib_in, W_EEb, W_IET, W_EIT, ext,
        g_ee, g_ei, g_ie, g_in, rate_e, rate_i,
        subk_e + t * MAX_POIS, subk_i + t * MAX_POIS,
        re_out, rb_out, ri_out, ib_out);
  }
}